// Round 3
// baseline (138.274 us; speedup 1.0000x reference)
//
#include <hip/hip_runtime.h>
#include <math.h>

// EnhancedFinancialGAT — analytical collapse (Round 0 proof: all N=2000 node
// rows identical + per-dst softmax sums to 1 (self-loop guarantees denom>=1)
// => each GAT layer is a dense 256->256 relu; edges/attention irrelevant).
//
// Round 9: actually kill the scratch spill. R8's __launch_bounds__(1024,4)
// only CAPS VGPRs at 128; the backend's occupancy heuristic still TARGETED
// 8 waves/EU (64 VGPRs) and spilled ~33 VGPRs/thread to reach it
// (WRITE_SIZE 8.7 MB on a 512 B-output kernel, VGPR_Count stuck at 64).
// amdgpu_waves_per_eu(4,4) pins min=max=4 waves/EU — the only occupancy a
// 1024-thread 1-block/CU launch can have (64 blocks on 256 CUs) — so the
// allocator gets the full 128-VGPR budget and no incentive to spill.

#define B_ITEMS 64

typedef _Float16 half_t;
typedef _Float16 half8 __attribute__((ext_vector_type(8)));

// ---- bias layout in LDS (float offsets) ----
#define BIN   0      // 256
#define BGAT  256    // 768 (3*256)
#define BFUSE 1024   // 256
#define BP1   1280   // 128
#define BD1   1408   // 128
#define BP2   1536   // 64
#define BD2   1600   // 64
#define NBIAS 1664

// Weight fragment for one layer: this lane's K-slice of its output row.
template <int K, int G>
struct WFrag { half8 w[K / (8 * G)]; };

// Load this lane's K-slice of output row o directly from the fp32 weight
// matrix [M][K], converting to fp16 in-register (RTN casts — bit-identical
// to the old compress_w prepass, so numerics are unchanged).
template <int K, int G>
__device__ __forceinline__ void load_frag(WFrag<K, G>& f,
                                          const float* __restrict__ W, int t) {
    const int c = t & (G - 1);
    const int o = t / G;
    const float4* __restrict__ W4 =
        reinterpret_cast<const float4*>(W + (size_t)o * K);
#pragma unroll
    for (int j = 0; j < K / (8 * G); ++j) {
        const int idx = j * G + c;
        float4 a = W4[2 * idx];
        float4 b = W4[2 * idx + 1];
        f.w[j] = half8{ (_Float16)a.x, (_Float16)a.y, (_Float16)a.z, (_Float16)a.w,
                        (_Float16)b.x, (_Float16)b.y, (_Float16)b.z, (_Float16)b.w };
    }
}

// out[M] = relu(frag @ in + b), frag already in registers. t in [0, M*G).
template <int M, int K, int G>
__device__ __forceinline__ void compute_frag(const WFrag<K, G>& f,
                                             const float* __restrict__ bias,  // LDS
                                             const float* __restrict__ in,    // LDS
                                             float* __restrict__ out,         // LDS
                                             int t) {
    const int c = t & (G - 1);
    const int o = t / G;
    const float4* __restrict__ A4 = reinterpret_cast<const float4*>(in);
    float acc = 0.f;
#pragma unroll
    for (int j = 0; j < K / (8 * G); ++j) {
        const int idx = j * G + c;
        float4 a0 = A4[2 * idx];
        float4 a1 = A4[2 * idx + 1];
        half8 w = f.w[j];
        acc = fmaf((float)w[0], a0.x, acc);
        acc = fmaf((float)w[1], a0.y, acc);
        acc = fmaf((float)w[2], a0.z, acc);
        acc = fmaf((float)w[3], a0.w, acc);
        acc = fmaf((float)w[4], a1.x, acc);
        acc = fmaf((float)w[5], a1.y, acc);
        acc = fmaf((float)w[6], a1.z, acc);
        acc = fmaf((float)w[7], a1.w, acc);
    }
#pragma unroll
    for (int s = 1; s < G; s <<= 1) acc += __shfl_xor(acc, s, 64);
    if (c == 0) out[o] = fmaxf(acc + bias[o], 0.f);
}

extern "C" __global__ __launch_bounds__(1024)
__attribute__((amdgpu_waves_per_eu(4, 4)))
void fin_gat_v9(
    const float* __restrict__ x,        // [64,64]
    const int* __restrict__ cidx,       // [64]
    const float* __restrict__ W_in,     // [256,64]
    const float* __restrict__ b_in,
    const float* __restrict__ gat_W,    // [3,256,256]
    const float* __restrict__ gat_b,    // [3,256]
    const float* __restrict__ emb,      // [2000,64]
    const float* __restrict__ W_fuse,   // [256,320]
    const float* __restrict__ b_fuse,
    const float* __restrict__ W_p1,     // [128,256]
    const float* __restrict__ b_p1,
    const float* __restrict__ W_p2,     // [64,128]
    const float* __restrict__ b_p2,
    const float* __restrict__ W_p3, const float* __restrict__ b_p3,
    const float* __restrict__ W_d1,     // [128,256]
    const float* __restrict__ b_d1,
    const float* __restrict__ W_d2,     // [64,128]
    const float* __restrict__ b_d2,
    const float* __restrict__ W_d3, const float* __restrict__ b_d3,
    float* __restrict__ out)            // [128]
{
    __shared__ float bufA[320];
    __shared__ float bufB[320];
    __shared__ float bias_lds[NBIAS];

    const int b = blockIdx.x;
    const int t = threadIdx.x;

    // ---- initial burst: L0 weights, x/emb, all biases, head dot weights ----
    WFrag<64, 4> f_in;
    load_frag(f_in, W_in, t);

    if (t < 64) {
        const int ci = cidx[b];
        bufA[t] = x[b * 64 + t];
        bufA[256 + t] = emb[(size_t)ci * 64 + t];   // kept for fuse layer
    }
    float wdot = 0.f, bdot = 0.f;
    if (t < 64)            wdot = W_p3[t];
    else if (t < 128)      wdot = W_d3[t - 64];
    if (t == 0)            bdot = b_p3[0];
    else if (t == 64)      bdot = b_d3[0];

#pragma unroll
    for (int i = t; i < NBIAS; i += 1024) {
        float v;
        if      (i < 256)  v = b_in[i];
        else if (i < 1024) v = gat_b[i - 256];
        else if (i < 1280) v = b_fuse[i - 1024];
        else if (i < 1408) v = b_p1[i - 1280];
        else if (i < 1536) v = b_d1[i - 1408];
        else if (i < 1600) v = b_p2[i - 1536];
        else               v = b_d2[i - 1600];
        bias_lds[i] = v;
    }
    __syncthreads();

    // ---- L0: h = relu(W_in x): A[0:64] -> B[0:256] ----
    WFrag<256, 4> fg0;
    load_frag(fg0, gat_W + 0 * 65536, t);                   // prefetch L1
    compute_frag<256, 64, 4>(f_in, bias_lds + BIN, bufA, bufB, t);
    __syncthreads();

    // ---- L1 (GAT1): B -> A[0:256]  (emb intact in A[256:320]) ----
    WFrag<256, 4> fg1;
    load_frag(fg1, gat_W + 1 * 65536, t);                   // prefetch L2
    compute_frag<256, 256, 4>(fg0, bias_lds + BGAT, bufB, bufA, t);
    __syncthreads();

    // ---- L2 (GAT2): A -> B ----
    WFrag<256, 4> fg2;
    load_frag(fg2, gat_W + 2 * 65536, t);                   // prefetch L3
    compute_frag<256, 256, 4>(fg1, bias_lds + BGAT + 256, bufA, bufB, t);
    __syncthreads();

    // ---- L3 (GAT3): B -> A[0:256] ----
    WFrag<320, 4> f_fu;
    load_frag(f_fu, W_fuse, t);                             // prefetch fuse
    compute_frag<256, 256, 4>(fg2, bias_lds + BGAT + 512, bufB, bufA, t);
    __syncthreads();

    // ---- L4 (fuse): A[0:320] -> B[0:256] ----
    WFrag<256, 4> f_h1;
    load_frag(f_h1, (t < 512) ? W_p1 : W_d1, t & 511);      // prefetch heads-1
    compute_frag<256, 320, 4>(f_fu, bias_lds + BFUSE, bufA, bufB, t);
    __syncthreads();

    // ---- L5: p1 (lower half-block) / d1 (upper half-block) ----
    WFrag<128, 8> f_h2;
    load_frag(f_h2, (t < 512) ? W_p2 : W_d2, t & 511);      // prefetch heads-2
    if (t < 512) compute_frag<128, 256, 4>(f_h1, bias_lds + BP1, bufB, bufA, t);
    else         compute_frag<128, 256, 4>(f_h1, bias_lds + BD1, bufB, bufA + 192, t - 512);
    __syncthreads();

    // ---- L6: p2 / d2 ----
    if (t < 512) compute_frag<64, 128, 8>(f_h2, bias_lds + BP2, bufA, bufB, t);
    else         compute_frag<64, 128, 8>(f_h2, bias_lds + BD2, bufA + 192, bufB + 64, t - 512);
    __syncthreads();

    // ---- final dots (weights preloaded): wave 0 -> price, wave 1 -> dir ----
    if (t < 64) {
        float v = wdot * bufB[t];
#pragma unroll
        for (int off = 32; off > 0; off >>= 1) v += __shfl_down(v, off, 64);
        if (t == 0) out[b] = v + bdot;
    } else if (t < 128) {
        const int u = t - 64;
        float v = wdot * bufB[64 + u];
#pragma unroll
        for (int off = 32; off > 0; off >>= 1) v += __shfl_down(v, off, 64);
        if (u == 0) {
            float z = v + bdot;
            out[B_ITEMS + b] = 1.0f / (1.0f + expf(-z));
        }
    }
}

extern "C" void kernel_launch(void* const* d_in, const int* in_sizes, int n_in,
                              void* d_out, int out_size, void* d_ws, size_t ws_size,
                              hipStream_t stream) {
    const float* x      = (const float*)d_in[0];
    const int*   cidx   = (const int*)  d_in[1];
    // d_in[2]=edge_index, d_in[3]=edge_attr -> numerically irrelevant
    const float* W_in   = (const float*)d_in[4];
    const float* b_in   = (const float*)d_in[5];
    const float* gat_W  = (const float*)d_in[6];
    // d_in[7..10] = att params -> irrelevant
    const float* gat_b  = (const float*)d_in[11];
    const float* emb    = (const float*)d_in[12];
    const float* W_fuse = (const float*)d_in[13];
    const float* b_fuse = (const float*)d_in[14];
    const float* W_p1   = (const float*)d_in[15];
    const float* b_p1   = (const float*)d_in[16];
    const float* W_p2   = (const float*)d_in[17];
    const float* b_p2   = (const float*)d_in[18];
    const float* W_p3   = (const float*)d_in[19];
    const float* b_p3   = (const float*)d_in[20];
    const float* W_d1   = (const float*)d_in[21];
    const float* b_d1   = (const float*)d_in[22];
    const float* W_d2   = (const float*)d_in[23];
    const float* b_d2   = (const float*)d_in[24];
    const float* W_d3   = (const float*)d_in[25];
    const float* b_d3   = (const float*)d_in[26];

    // d_ws unused: the fp16 compression is done in-register at load time
    // (workspace is re-poisoned every iteration, so a prepass could never be
    // hoisted anyway).
    (void)d_ws; (void)ws_size;

    fin_gat_v9<<<B_ITEMS, 1024, 0, stream>>>(
        x, cidx, W_in, b_in, gat_W, gat_b, emb, W_fuse, b_fuse,
        W_p1, b_p1, W_p2, b_p2, W_p3, b_p3,
        W_d1, b_d1, W_d2, b_d2, W_d3, b_d3,
        (float*)d_out);
}

// Round 4
// 131.894 us; speedup vs baseline: 1.0484x; 1.0484x over previous
//
#include <hip/hip_runtime.h>
#include <math.h>

// EnhancedFinancialGAT — analytical collapse (Round 0 proof: all N=2000 node
// rows identical + per-dst softmax sums to 1 (self-loop guarantees denom>=1)
// => each GAT layer is a dense 256->256 relu; edges/attention irrelevant).
//
// Round 10: LDS-staged weight pipeline. R7-R9 showed the register-prefetch
// structure with fp32 source loads needs ~128 VGPRs but the allocator pins
// 64 and spills ~33/thread (8.5 MB scratch writes/dispatch) — and no
// attribute moves it. Fix: remove register pressure at the source. Weights
// stream global->LDS via __builtin_amdgcn_global_load_lds (no VGPR temps),
// double-buffered 64 KB stages, counted s_waitcnt vmcnt(4) + raw s_barrier
// (never drain the pipe), compute reads weights straight from LDS.
// The whole net = 23 uniform 64 KB stages; fp32 end-to-end (no fp16).

#define B_ITEMS 64

// ---- bias layout in LDS (float offsets) ----
#define BIN   0      // 256
#define BGAT  256    // 768 (3*256)
#define BFUSE 1024   // 256
#define BP1   1280   // 128
#define BD1   1408   // 128
#define BP2   1536   // 64
#define BD2   1600   // 64
#define NBIAS 1664

// async 16B global->LDS copy (no VGPR destination, vmcnt-counted)
__device__ __forceinline__ void g2l16(const float* g, float* l) {
    __builtin_amdgcn_global_load_lds(
        (const __attribute__((address_space(1))) void*)g,
        (__attribute__((address_space(3))) void*)l, 16, 0, 0);
}

// Issue one 64 KB stage: 4096 float4 slots, thread t covers slots
// {t, 1024+t, 2048+t, 3072+t}. Slot n -> (row r = n>>LOGQ, chunk q).
// LDS layout is linear [M][K] floats (matches slot order: wave-uniform base
// + lane*16, per m104). rs = global row stride in floats.
template <int LOGQ>
__device__ __forceinline__ void issue(const float* __restrict__ gbase, int rs,
                                      float* lbuf, int t) {
#pragma unroll
    for (int i = 0; i < 4; ++i) {
        const int n = i * 1024 + t;
        const int r = n >> LOGQ;
        const int q = n & ((1 << LOGQ) - 1);
        g2l16(gbase + (size_t)r * rs + q * 4, lbuf + (size_t)n * 4);
    }
}

// pd2 stage: virtual [128x128] = [W_p2 (64x128); W_d2 (64x128)], rs=128.
__device__ __forceinline__ void issue_split(const float* __restrict__ gA,
                                            const float* __restrict__ gB,
                                            float* lbuf, int t) {
#pragma unroll
    for (int i = 0; i < 4; ++i) {
        const int n = i * 1024 + t;
        const int r = n >> 5;
        const int q = n & 31;
        const float* g = (r < 64) ? (gA + (size_t)r * 128 + q * 4)
                                  : (gB + (size_t)(r - 64) * 128 + q * 4);
        g2l16(g, lbuf + (size_t)n * 4);
    }
}

// Stage GEMV: M rows (M*G == 1024), K cols, G lanes/row; K/(4G) == 4 float4
// iterations for every stage shape used. MODE 0: relu(acc+bias);
// MODE 1: raw partial (no bias/relu); MODE 2: relu(acc+accin+bias).
template <int K, int G, int MODE>
__device__ __forceinline__ void comp(const float* wt,          // LDS [M][K]
                                     const float* vin,         // LDS [K]
                                     float* vout,              // LDS [M]
                                     const float* bias,        // LDS or null
                                     const float* accin,       // LDS or null
                                     int t) {
    const int c = t & (G - 1);
    const int o = t / G;
    const float4* W4 = reinterpret_cast<const float4*>(wt + (size_t)o * K);
    const float4* A4 = reinterpret_cast<const float4*>(vin);
    float acc = 0.f;
#pragma unroll
    for (int j = 0; j < K / (4 * G); ++j) {
        const int idx = j * G + c;
        float4 w = W4[idx];
        float4 a = A4[idx];
        acc = fmaf(w.x, a.x, acc);
        acc = fmaf(w.y, a.y, acc);
        acc = fmaf(w.z, a.z, acc);
        acc = fmaf(w.w, a.w, acc);
    }
#pragma unroll
    for (int s = 1; s < G; s <<= 1) acc += __shfl_xor(acc, s, 64);
    if (c == 0) {
        if constexpr (MODE == 0)      vout[o] = fmaxf(acc + bias[o], 0.f);
        else if constexpr (MODE == 1) vout[o] = acc;
        else                          vout[o] = fmaxf(acc + accin[o] + bias[o], 0.f);
    }
}

// pd2 compute: M=128 (rows 0-63 = p2 read vin[0:128], 64-127 = d2 read
// vin[128:256]), K=128, G=8.
__device__ __forceinline__ void comp_pd2(const float* wt, const float* vin,
                                         float* vout, const float* bias_base,
                                         int t) {
    const int c = t & 7;
    const int o = t >> 3;                       // 0..127
    const float* vi = vin + ((o < 64) ? 0 : 128);
    const float* bi = (o < 64) ? (bias_base + BP2) : (bias_base + BD2 - 64);
    const float4* W4 = reinterpret_cast<const float4*>(wt + (size_t)o * 128);
    const float4* A4 = reinterpret_cast<const float4*>(vi);
    float acc = 0.f;
#pragma unroll
    for (int j = 0; j < 4; ++j) {
        const int idx = j * 8 + c;
        float4 w = W4[idx];
        float4 a = A4[idx];
        acc = fmaf(w.x, a.x, acc);
        acc = fmaf(w.y, a.y, acc);
        acc = fmaf(w.z, a.z, acc);
        acc = fmaf(w.w, a.w, acc);
    }
#pragma unroll
    for (int s = 1; s < 8; s <<= 1) acc += __shfl_xor(acc, s, 64);
    if (c == 0) vout[o] = fmaxf(acc + bi[o], 0.f);
}

// One pipeline step: issue next stage's DMA (into the OTHER buffer — safe,
// last reader finished before the previous closing barrier), wait for the
// CURRENT stage's 4 DMA instructions (vmcnt(WAITN) leaves the 4 just
// issued in flight — never drain), raw barrier (no compiler vmcnt(0)
// drain, unlike __syncthreads), compute, fence LDS writes, barrier.
#define STEP(ISSUE_STMT, WAITN, COMP_STMT)                                   \
    do {                                                                     \
        ISSUE_STMT;                                                          \
        asm volatile("s_waitcnt vmcnt(" WAITN ")" ::: "memory");             \
        __builtin_amdgcn_sched_barrier(0);                                   \
        __builtin_amdgcn_s_barrier();                                        \
        COMP_STMT;                                                           \
        asm volatile("s_waitcnt lgkmcnt(0)" ::: "memory");                   \
        __builtin_amdgcn_s_barrier();                                        \
        __builtin_amdgcn_sched_barrier(0);                                   \
    } while (0)

extern "C" __global__ __launch_bounds__(1024) void fin_gat_v10(
    const float* __restrict__ x,        // [64,64]
    const int* __restrict__ cidx,       // [64]
    const float* __restrict__ W_in,     // [256,64]
    const float* __restrict__ b_in,
    const float* __restrict__ gat_W,    // [3,256,256]
    const float* __restrict__ gat_b,    // [3,256]
    const float* __restrict__ emb,      // [2000,64]
    const float* __restrict__ W_fuse,   // [256,320]
    const float* __restrict__ b_fuse,
    const float* __restrict__ W_p1,     // [128,256]
    const float* __restrict__ b_p1,
    const float* __restrict__ W_p2,     // [64,128]
    const float* __restrict__ b_p2,
    const float* __restrict__ W_p3, const float* __restrict__ b_p3,
    const float* __restrict__ W_d1,     // [128,256]
    const float* __restrict__ b_d1,
    const float* __restrict__ W_d2,     // [64,128]
    const float* __restrict__ b_d2,
    const float* __restrict__ W_d3, const float* __restrict__ b_d3,
    float* __restrict__ out)            // [128]
{
    __shared__ float wbuf[2][16384];    // 2 x 64 KB weight stages
    __shared__ float vec0[256];
    __shared__ float vec1[256];
    __shared__ float xvec[64];
    __shared__ float embvec[64];
    __shared__ float accbuf[256];
    __shared__ float bias_lds[NBIAS];

    const int b = blockIdx.x;
    const int t = threadIdx.x;
    float* const wA = &wbuf[0][0];
    float* const wB = &wbuf[1][0];
    const float* const BL = bias_lds;

    // ---- prologue: start S0 DMA first, then scalars/biases, full sync ----
    issue<4>(W_in, 64, wA, t);                      // S0: W_in [256x64]

    if (t < 64) {
        const int ci = cidx[b];
        xvec[t]   = x[b * 64 + t];
        embvec[t] = emb[(size_t)ci * 64 + t];
    }
    float wdot = 0.f, bdot = 0.f;
    if (t < 64)            wdot = W_p3[t];
    else if (t < 128)      wdot = W_d3[t - 64];
    if (t == 0)            bdot = b_p3[0];
    else if (t == 64)      bdot = b_d3[0];

#pragma unroll
    for (int i = t; i < NBIAS; i += 1024) {
        float v;
        if      (i < 256)  v = b_in[i];
        else if (i < 1024) v = gat_b[i - 256];
        else if (i < 1280) v = b_fuse[i - 1024];
        else if (i < 1408) v = b_p1[i - 1280];
        else if (i < 1536) v = b_d1[i - 1408];
        else if (i < 1600) v = b_p2[i - 1536];
        else               v = b_d2[i - 1600];
        bias_lds[i] = v;
    }
    __syncthreads();    // drains everything incl. S0 DMA; pipeline invariant:
                        // entering the loop, outstanding vmcnt == 0.

    const float* gW0 = gat_W;
    const float* gW1 = gat_W + 65536;
    const float* gW2 = gat_W + 131072;

    // ---- 23-stage pipeline (stage i in wA/wB alternating, even->wA) ----
    // S0: in layer
    STEP(issue<6>(gW0,            256, wB, t), "4", (comp<64, 4, 0>(wA, xvec, vec0, BL + BIN, nullptr, t)));
    // S1-S4: GAT layer 0 (vec0 -> vec1)
    STEP(issue<6>(gW0 +  64*256,  256, wA, t), "4", (comp<256,16, 0>(wB, vec0, vec1 +   0, BL + BGAT +   0, nullptr, t)));
    STEP(issue<6>(gW0 + 128*256,  256, wB, t), "4", (comp<256,16, 0>(wA, vec0, vec1 +  64, BL + BGAT +  64, nullptr, t)));
    STEP(issue<6>(gW0 + 192*256,  256, wA, t), "4", (comp<256,16, 0>(wB, vec0, vec1 + 128, BL + BGAT + 128, nullptr, t)));
    STEP(issue<6>(gW1,            256, wB, t), "4", (comp<256,16, 0>(wA, vec0, vec1 + 192, BL + BGAT + 192, nullptr, t)));
    // S5-S8: GAT layer 1 (vec1 -> vec0)
    STEP(issue<6>(gW1 +  64*256,  256, wA, t), "4", (comp<256,16, 0>(wB, vec1, vec0 +   0, BL + BGAT + 256,       nullptr, t)));
    STEP(issue<6>(gW1 + 128*256,  256, wB, t), "4", (comp<256,16, 0>(wA, vec1, vec0 +  64, BL + BGAT + 256 +  64, nullptr, t)));
    STEP(issue<6>(gW1 + 192*256,  256, wA, t), "4", (comp<256,16, 0>(wB, vec1, vec0 + 128, BL + BGAT + 256 + 128, nullptr, t)));
    STEP(issue<6>(gW2,            256, wB, t), "4", (comp<256,16, 0>(wA, vec1, vec0 + 192, BL + BGAT + 256 + 192, nullptr, t)));
    // S9-S12: GAT layer 2 (vec0 -> vec1)
    STEP(issue<6>(gW2 +  64*256,  256, wA, t), "4", (comp<256,16, 0>(wB, vec0, vec1 +   0, BL + BGAT + 512,       nullptr, t)));
    STEP(issue<6>(gW2 + 128*256,  256, wB, t), "4", (comp<256,16, 0>(wA, vec0, vec1 +  64, BL + BGAT + 512 +  64, nullptr, t)));
    STEP(issue<6>(gW2 + 192*256,  256, wA, t), "4", (comp<256,16, 0>(wB, vec0, vec1 + 128, BL + BGAT + 512 + 128, nullptr, t)));
    STEP(issue<6>(W_fuse,         320, wB, t), "4", (comp<256,16, 0>(wA, vec0, vec1 + 192, BL + BGAT + 512 + 192, nullptr, t)));
    // S13-S16: fuse, cols 0-255 (vec1 -> accbuf partials, no bias/relu yet)
    STEP(issue<6>(W_fuse +  64*320, 320, wA, t), "4", (comp<256,16, 1>(wB, vec1, accbuf +   0, nullptr, nullptr, t)));
    STEP(issue<6>(W_fuse + 128*320, 320, wB, t), "4", (comp<256,16, 1>(wA, vec1, accbuf +  64, nullptr, nullptr, t)));
    STEP(issue<6>(W_fuse + 192*320, 320, wA, t), "4", (comp<256,16, 1>(wB, vec1, accbuf + 128, nullptr, nullptr, t)));
    STEP(issue<4>(W_fuse + 256,     320, wB, t), "4", (comp<256,16, 1>(wA, vec1, accbuf + 192, nullptr, nullptr, t)));
    // S17: fuse, emb cols 256-319 ([256x64], K=64) + partials + bias + relu
    STEP(issue<6>(W_p1,           256, wA, t), "4", (comp<64, 4, 2>(wB, embvec, vec0, BL + BFUSE, accbuf, t)));
    // S18-S21: p1 rows 0-127, d1 rows 0-127 (vec0 -> vec1)
    STEP(issue<6>(W_p1 + 64*256,  256, wB, t), "4", (comp<256,16, 0>(wA, vec0, vec1 +   0, BL + BP1,      nullptr, t)));
    STEP(issue<6>(W_d1,           256, wA, t), "4", (comp<256,16, 0>(wB, vec0, vec1 +  64, BL + BP1 + 64, nullptr, t)));
    STEP(issue<6>(W_d1 + 64*256,  256, wB, t), "4", (comp<256,16, 0>(wA, vec0, vec1 + 128, BL + BD1,      nullptr, t)));
    STEP(issue_split(W_p2, W_d2,       wA, t), "4", (comp<256,16, 0>(wB, vec0, vec1 + 192, BL + BD1 + 64, nullptr, t)));
    // S22: p2/d2 ([128x128] split) -> vec0[0:128]
    STEP((void)0,                              "0", (comp_pd2(wA, vec1, vec0, BL, t)));

    // ---- final dots: wave 0 -> price, wave 1 -> direction ----
    if (t < 64) {
        float v = wdot * vec0[t];
#pragma unroll
        for (int off = 32; off > 0; off >>= 1) v += __shfl_down(v, off, 64);
        if (t == 0) out[b] = v + bdot;
    } else if (t < 128) {
        const int u = t - 64;
        float v = wdot * vec0[64 + u];
#pragma unroll
        for (int off = 32; off > 0; off >>= 1) v += __shfl_down(v, off, 64);
        if (u == 0) {
            float z = v + bdot;
            out[B_ITEMS + b] = 1.0f / (1.0f + expf(-z));
        }
    }
}

extern "C" void kernel_launch(void* const* d_in, const int* in_sizes, int n_in,
                              void* d_out, int out_size, void* d_ws, size_t ws_size,
                              hipStream_t stream) {
    const float* x      = (const float*)d_in[0];
    const int*   cidx   = (const int*)  d_in[1];
    // d_in[2]=edge_index, d_in[3]=edge_attr -> numerically irrelevant
    const float* W_in   = (const float*)d_in[4];
    const float* b_in   = (const float*)d_in[5];
    const float* gat_W  = (const float*)d_in[6];
    // d_in[7..10] = att params -> irrelevant
    const float* gat_b  = (const float*)d_in[11];
    const float* emb    = (const float*)d_in[12];
    const float* W_fuse = (const float*)d_in[13];
    const float* b_fuse = (const float*)d_in[14];
    const float* W_p1   = (const float*)d_in[15];
    const float* b_p1   = (const float*)d_in[16];
    const float* W_p2   = (const float*)d_in[17];
    const float* b_p2   = (const float*)d_in[18];
    const float* W_p3   = (const float*)d_in[19];
    const float* b_p3   = (const float*)d_in[20];
    const float* W_d1   = (const float*)d_in[21];
    const float* b_d1   = (const float*)d_in[22];
    const float* W_d2   = (const float*)d_in[23];
    const float* b_d2   = (const float*)d_in[24];
    const float* W_d3   = (const float*)d_in[25];
    const float* b_d3   = (const float*)d_in[26];

    (void)d_ws; (void)ws_size;   // unused: fp32 weights stream via LDS DMA

    fin_gat_v10<<<B_ITEMS, 1024, 0, stream>>>(
        x, cidx, W_in, b_in, gat_W, gat_b, emb, W_fuse, b_fuse,
        W_p1, b_p1, W_p2, b_p2, W_p3, b_p3,
        W_d1, b_d1, W_d2, b_d2, W_d3, b_d3,
        (float*)d_out);
}

// Round 5
// 124.779 us; speedup vs baseline: 1.1082x; 1.0570x over previous
//
#include <hip/hip_runtime.h>
#include <math.h>

// EnhancedFinancialGAT — analytical collapse (Round 0 proof: all N=2000 node
// rows identical + per-dst softmax sums to 1 (self-loop guarantees denom>=1)
// => each GAT layer is a dense 256->256 relu; edges/attention irrelevant).
//
// Round 11: weights never touch LDS. R10's LDS-staged pipeline was limited
// by the LDS port itself: every weight byte cost an LDS write (DMA) + an
// LDS read (ds_read_b128), ~128 instr-wave x 12cyc per 64KB stage across 23
// barrier-serialized stages ~= 35us kernel. Weights have ZERO reuse within a
// block (one activation vector, not a tile), so stream them global->VGPR->FMA
// through the idle L1/TA path instead. Only the 320-float activation vector
// lives in LDS (broadcast reads ~ free). Chunked loads (4 float4 in flight,
// rolled outer loop) keep pressure ~30 VGPRs — no spill at the 64-VGPR
// allocation that sank v7-v9. 7 barriers total (vs 46). fp32 end-to-end.

#define B_ITEMS 64

// One dense layer slice: thread owns output row o (G lanes split K).
// Wrow = global base of row o; bv = bias[o]; vin = LDS activation [K].
// Loads are chunked (CH=4 float4 in flight) with a rolled outer loop to
// bound register pressure; 16 waves of TLP hide the L2-hit latency.
template <int K, int G, bool RELU>
__device__ __forceinline__ void layer_g(
    const float* __restrict__ Wrow,
    float bv,
    const float* __restrict__ vin,    // LDS [K]
    float* __restrict__ vout,         // LDS
    int o, int c) {
    const float4* __restrict__ W4 = reinterpret_cast<const float4*>(Wrow);
    const float4* __restrict__ A4 = reinterpret_cast<const float4*>(vin);
    constexpr int NJ = K / (4 * G);
    constexpr int CH = (NJ >= 4) ? 4 : NJ;
    float acc = 0.f;
#pragma unroll 1
    for (int jj = 0; jj < NJ; jj += CH) {
        float4 w[CH], a[CH];
#pragma unroll
        for (int u = 0; u < CH; ++u) {
            const int idx = (jj + u) * G + c;
            w[u] = W4[idx];
            a[u] = A4[idx];
        }
#pragma unroll
        for (int u = 0; u < CH; ++u) {
            acc = fmaf(w[u].x, a[u].x, acc);
            acc = fmaf(w[u].y, a[u].y, acc);
            acc = fmaf(w[u].z, a[u].z, acc);
            acc = fmaf(w[u].w, a[u].w, acc);
        }
    }
#pragma unroll
    for (int s = 1; s < G; s <<= 1) acc += __shfl_xor(acc, s, 64);
    if (c == 0) {
        const float r = acc + bv;
        vout[o] = RELU ? fmaxf(r, 0.f) : r;
    }
}

extern "C" __global__ __launch_bounds__(1024) void fin_gat_v11(
    const float* __restrict__ x,        // [64,64]
    const int* __restrict__ cidx,       // [64]
    const float* __restrict__ W_in,     // [256,64]
    const float* __restrict__ b_in,
    const float* __restrict__ gat_W,    // [3,256,256]
    const float* __restrict__ gat_b,    // [3,256]
    const float* __restrict__ emb,      // [2000,64]
    const float* __restrict__ W_fuse,   // [256,320]
    const float* __restrict__ b_fuse,
    const float* __restrict__ W_p1,     // [128,256]
    const float* __restrict__ b_p1,
    const float* __restrict__ W_p2,     // [64,128]
    const float* __restrict__ b_p2,
    const float* __restrict__ W_p3, const float* __restrict__ b_p3,
    const float* __restrict__ W_d1,     // [128,256]
    const float* __restrict__ b_d1,
    const float* __restrict__ W_d2,     // [64,128]
    const float* __restrict__ b_d2,
    const float* __restrict__ W_d3, const float* __restrict__ b_d3,
    float* __restrict__ out)            // [128]
{
    __shared__ float vecA[320];   // activations; emb parked at [256:320]
    __shared__ float vecB[256];
    __shared__ float xvec[64];

    const int b = blockIdx.x;
    const int t = threadIdx.x;
    const int o4 = t >> 2, c4 = t & 3;

    // ---- prologue: x, emb, head-dot weights (all independent loads) ----
    if (t < 64) {
        const int ci = cidx[b];
        xvec[t] = x[b * 64 + t];
        vecA[256 + t] = emb[(size_t)ci * 64 + t];
    }
    float wdot = 0.f, bdot = 0.f;
    if (t < 64)            wdot = W_p3[t];
    else if (t < 128)      wdot = W_d3[t - 64];
    if (t == 0)            bdot = b_p3[0];
    else if (t == 64)      bdot = b_d3[0];
    __syncthreads();

    // ---- L0: relu(W_in x): xvec -> vecB[0:256] ----
    layer_g<64, 4, true>(W_in + (size_t)o4 * 64, b_in[o4], xvec, vecB, o4, c4);
    __syncthreads();

    // ---- GAT0: vecB -> vecA[0:256] (emb at [256:320] untouched) ----
    layer_g<256, 4, true>(gat_W + (size_t)o4 * 256, gat_b[o4],
                          vecB, vecA, o4, c4);
    __syncthreads();

    // ---- GAT1: vecA -> vecB ----
    layer_g<256, 4, true>(gat_W + 65536 + (size_t)o4 * 256, gat_b[256 + o4],
                          vecA, vecB, o4, c4);
    __syncthreads();

    // ---- GAT2: vecB -> vecA[0:256] ----
    layer_g<256, 4, true>(gat_W + 131072 + (size_t)o4 * 256, gat_b[512 + o4],
                          vecB, vecA, o4, c4);
    __syncthreads();

    // ---- FUSE: vecA[0:320] (gat3 out ++ emb) -> vecB ----
    layer_g<320, 4, true>(W_fuse + (size_t)o4 * 320, b_fuse[o4],
                          vecA, vecB, o4, c4);
    __syncthreads();

    // ---- P1 ++ D1 (virtual 256 rows): vecB -> vecA[0:256] ----
    {
        const float* Wr = (o4 < 128) ? (W_p1 + (size_t)o4 * 256)
                                     : (W_d1 + (size_t)(o4 - 128) * 256);
        const float bv = (o4 < 128) ? b_p1[o4] : b_d1[o4 - 128];
        layer_g<256, 4, true>(Wr, bv, vecB, vecA, o4, c4);
    }
    __syncthreads();

    // ---- P2 ++ D2 (virtual 128 rows, K=128): vecA -> vecB[0:128] ----
    {
        const int o8 = t >> 3, c8 = t & 7;
        const float* Wr = (o8 < 64) ? (W_p2 + (size_t)o8 * 128)
                                    : (W_d2 + (size_t)(o8 - 64) * 128);
        const float bv = (o8 < 64) ? b_p2[o8] : b_d2[o8 - 64];
        const float* vi = vecA + ((o8 < 64) ? 0 : 128);
        layer_g<128, 8, true>(Wr, bv, vi, vecB, o8, c8);
    }
    __syncthreads();

    // ---- final dots: wave 0 -> price, wave 1 -> direction ----
    if (t < 64) {
        float v = wdot * vecB[t];
#pragma unroll
        for (int off = 32; off > 0; off >>= 1) v += __shfl_down(v, off, 64);
        if (t == 0) out[b] = v + bdot;
    } else if (t < 128) {
        const int u = t - 64;
        float v = wdot * vecB[64 + u];
#pragma unroll
        for (int off = 32; off > 0; off >>= 1) v += __shfl_down(v, off, 64);
        if (u == 0) {
            float z = v + bdot;
            out[B_ITEMS + b] = 1.0f / (1.0f + expf(-z));
        }
    }
}

extern "C" void kernel_launch(void* const* d_in, const int* in_sizes, int n_in,
                              void* d_out, int out_size, void* d_ws, size_t ws_size,
                              hipStream_t stream) {
    const float* x      = (const float*)d_in[0];
    const int*   cidx   = (const int*)  d_in[1];
    // d_in[2]=edge_index, d_in[3]=edge_attr -> numerically irrelevant
    const float* W_in   = (const float*)d_in[4];
    const float* b_in   = (const float*)d_in[5];
    const float* gat_W  = (const float*)d_in[6];
    // d_in[7..10] = att params -> irrelevant
    const float* gat_b  = (const float*)d_in[11];
    const float* emb    = (const float*)d_in[12];
    const float* W_fuse = (const float*)d_in[13];
    const float* b_fuse = (const float*)d_in[14];
    const float* W_p1   = (const float*)d_in[15];
    const float* b_p1   = (const float*)d_in[16];
    const float* W_p2   = (const float*)d_in[17];
    const float* b_p2   = (const float*)d_in[18];
    const float* W_p3   = (const float*)d_in[19];
    const float* b_p3   = (const float*)d_in[20];
    const float* W_d1   = (const float*)d_in[21];
    const float* b_d1   = (const float*)d_in[22];
    const float* W_d2   = (const float*)d_in[23];
    const float* b_d2   = (const float*)d_in[24];
    const float* W_d3   = (const float*)d_in[25];
    const float* b_d3   = (const float*)d_in[26];

    (void)d_ws; (void)ws_size;   // unused: weights stream global->VGPR->FMA

    fin_gat_v11<<<B_ITEMS, 1024, 0, stream>>>(
        x, cidx, W_in, b_in, gat_W, gat_b, emb, W_fuse, b_fuse,
        W_p1, b_p1, W_p2, b_p2, W_p3, b_p3,
        W_d1, b_d1, W_d2, b_d2, W_d3, b_d3,
        (float*)d_out);
}